// Round 9
// baseline (114.041 us; speedup 1.0000x reference)
//
#include <hip/hip_runtime.h>
#include <hip/hip_cooperative_groups.h>

namespace cg = cooperative_groups;

// RGBuvHistBlock: soft histogram, 64 bins in [-1,1], sigma=0.02.
// WIN=+/-2 bins (measured absmax 1.22e-4 vs threshold 3.42e-4; WIN=1 would
// exclude e^-2.83~0.06 weights -> fail). Per pixel: k = rint(63x), exp2(d^2*C)
// for bins k-2..k+2, accumulated into a PER-THREAD private LDS column (no
// atomics: shared-float atomicAdd = CAS loop, 72us in R3). R8 showed DS-op
// count is NOT the binding cost (-29% ops -> -0.5% time); remaining lever is
// dispatch count -> single cooperative kernel (accum + grid.sync + norm).

#define NCH   24        // 8*3 channels
#define HW    65536     // 256*256
#define BPC   32        // blocks per channel
#define NBIN  64
#define NROWS 68        // 2 guard + 64 bins + 2 guard
#define NCOL  128       // one column per thread; bank = t%32, 2 lanes/bank = free
#define DELTA (2.0f / 63.0f)
// C = -1/(2*sigma^2) * log2(e) = -1250 * 1.4426950408889634
#define EXP_C (-1803.3688011112042f)

__device__ __forceinline__ void accum_body(const float* __restrict__ x,
                                           float* __restrict__ part,
                                           float (*hist)[NCOL]) {
    const int ch  = blockIdx.x >> 5;
    const int sub = blockIdx.x & 31;
    const int tid = threadIdx.x;

    // zero-init: 68*128 = 8704 words = 2176 float4; 128 threads x 17
    float4* hz = reinterpret_cast<float4*>(&hist[0][0]);
#pragma unroll
    for (int i = 0; i < 17; ++i) hz[i * 128 + tid] = float4{0.f, 0.f, 0.f, 0.f};
    __syncthreads();

    // 2048 px per block; 128 threads x 4 float4 (16 px/thread), coalesced
    const float4* xv = reinterpret_cast<const float4*>(x) + ch * (HW / 4) + sub * 512;
    float4 v[4];
#pragma unroll
    for (int i = 0; i < 4; ++i) v[i] = xv[i * 128 + tid];

#pragma unroll
    for (int i = 0; i < 4; ++i) {
        float px[4] = {v[i].x, v[i].y, v[i].z, v[i].w};
#pragma unroll
        for (int q = 0; q < 4; ++q) {
            const float pp = 63.0f * px[q];
            const float kf = rintf(pp);
            const float d0 = (pp - kf) * DELTA;  // p - nearest bin val
            const int   ki = (int)kf;            // 0..63
            // rows ki..ki+4 == bins ki-2..ki+2 shifted by +2 guard rows
            float* base = &hist[0][threadIdx.x] + ki * NCOL;
            float w[5];
#pragma unroll
            for (int m = 0; m < 5; ++m) {
                const float d = d0 - (float)(m - 2) * DELTA;
                w[m] = __builtin_amdgcn_exp2f(d * (d * EXP_C));
            }
#pragma unroll
            for (int m = 0; m < 5; ++m) base[m * NCOL] += w[m];
        }
    }
    __syncthreads();

    // reduce 128 columns per bin; wave w -> bins w*32..w*32+31, 2 bins/iter.
    const int wid  = tid >> 6;
    const int lane = tid & 63;
    const int half = lane >> 5;
    const int l32  = lane & 31;
    float* pout = part + (ch * BPC + sub) * NBIN;
#pragma unroll
    for (int g = 0; g < 16; ++g) {
        const int bin = wid * 32 + 2 * g + half;
        const float4 r4 = *reinterpret_cast<const float4*>(&hist[bin + 2][l32 * 4]);
        float s = (r4.x + r4.y) + (r4.z + r4.w);
        s += __shfl_xor(s, 1);
        s += __shfl_xor(s, 2);
        s += __shfl_xor(s, 4);
        s += __shfl_xor(s, 8);
        s += __shfl_xor(s, 16);   // stays within each 32-lane half
        if (l32 == 0) pout[bin] = s;
    }
}

__global__ __launch_bounds__(128) void hist_fused(const float* __restrict__ x,
                                                  float* __restrict__ part,
                                                  float* __restrict__ out) {
    __shared__ float hist[NROWS][NCOL];          // 34.8 KB -> 4 blocks/CU, 768 co-resident
    accum_body(x, part, hist);

    cg::this_grid().sync();                      // device-scope barrier + fence

    if (blockIdx.x < NCH) {                      // blocks 0..23: normalize
        const int ch  = blockIdx.x;
        const int tid = threadIdx.x;
        const int bin = tid & 63;
        const int grp = tid >> 6;                // 0..1
        const float* p = part + ch * (BPC * NBIN);
        float s = 0.0f;
#pragma unroll
        for (int i = 0; i < 16; ++i)             // each grp sums 16 of 32 sub-partials
            s += p[(grp * 16 + i) * NBIN + bin];
        float* sacc = &hist[0][0];               // reuse hist LDS (this block is past accum)
        sacc[grp * 64 + bin] = s;
        __syncthreads();
        if (grp == 0) {
            const float h = sacc[bin] + sacc[64 + bin];
            float tot = h;
            tot += __shfl_xor(tot, 32);
            tot += __shfl_xor(tot, 16);
            tot += __shfl_xor(tot, 8);
            tot += __shfl_xor(tot, 4);
            tot += __shfl_xor(tot, 2);
            tot += __shfl_xor(tot, 1);
            out[ch * NBIN + bin] = h / (tot + 1e-8f);
        }
    }
}

// ---- fallback path (proven R8 kernels), used only if cooperative launch fails ----
__global__ __launch_bounds__(128) void hist_accum(const float* __restrict__ x,
                                                  float* __restrict__ part) {
    __shared__ float hist[NROWS][NCOL];
    accum_body(x, part, hist);
}

__global__ __launch_bounds__(256) void hist_norm(const float* __restrict__ part,
                                                 float* __restrict__ out) {
    const int ch  = blockIdx.x;
    const int t   = threadIdx.x;
    const int bin = t & 63;
    const int grp = t >> 6;            // 0..3
    const float* p = part + ch * (BPC * NBIN);
    float s = 0.0f;
#pragma unroll
    for (int i = 0; i < 8; ++i)
        s += p[(grp * 8 + i) * NBIN + bin];
    __shared__ float sacc[4][NBIN];
    sacc[grp][bin] = s;
    __syncthreads();
    if (grp == 0) {
        const float h = sacc[0][bin] + sacc[1][bin] + sacc[2][bin] + sacc[3][bin];
        float tot = h;
        tot += __shfl_xor(tot, 32);
        tot += __shfl_xor(tot, 16);
        tot += __shfl_xor(tot, 8);
        tot += __shfl_xor(tot, 4);
        tot += __shfl_xor(tot, 2);
        tot += __shfl_xor(tot, 1);
        out[ch * NBIN + bin] = h / (tot + 1e-8f);
    }
}

extern "C" void kernel_launch(void* const* d_in, const int* in_sizes, int n_in,
                              void* d_out, int out_size, void* d_ws, size_t ws_size,
                              hipStream_t stream) {
    const float* x  = (const float*)d_in[0];
    float* part     = (float*)d_ws;    // 24*32*64*4 = 192 KB, fully overwritten
    float* outp     = (float*)d_out;

    void* args[] = {(void*)&x, (void*)&part, (void*)&outp};
    hipError_t e = hipLaunchCooperativeKernel((const void*)hist_fused,
                                              dim3(NCH * BPC), dim3(128),
                                              args, 0, stream);
    if (e != hipSuccess) {             // deterministic fallback: two-kernel path
        hist_accum<<<NCH * BPC, 128, 0, stream>>>(x, part);
        hist_norm<<<NCH, 256, 0, stream>>>(part, outp);
    }
}

// Round 10
// 96.757 us; speedup vs baseline: 1.1786x; 1.1786x over previous
//
#include <hip/hip_runtime.h>

// RGBuvHistBlock: soft histogram, 64 bins in [-1,1], sigma=0.02.
// WIN=+/-2 bins (measured absmax 1.22e-4 vs threshold 3.42e-4).
// Per pixel: k = rint(63x), w_m = exp2(d^2*C) for bins k-2..k+2, accumulated
// into a PER-WAVE 64-bin LDS row via native ds_add_f32 (inline asm).
// History: HIP atomicAdd(shared float) = CAS loop -> 71.7us (R3).
//          Thread-private-column RMW (no atomics) -> ~10.3us (R4/R8).
//          grid.sync() fusion -> +50us total (R9) -> reverted.
// ds_add_f32 is fire-and-forget (no return, no read-latency chain, no CAS
// retries); uniform input -> ~2 lanes/bank per add = free (m136).
// LDS addr idiom: low 32 bits of a generic pointer to __shared__ == DS byte
// offset (shared aperture is 2^32-aligned) — standard CK/HK inline-asm idiom.

#define NCH   24        // 8*3 channels
#define HW    65536     // 256*256
#define BPC   64        // blocks per channel (1024 px each)
#define NBIN  64
#define DELTA (2.0f / 63.0f)
// C = -1/(2*sigma^2) * log2(e) = -1250 * 1.4426950408889634
#define EXP_C (-1803.3688011112042f)

__global__ __launch_bounds__(256) void hist_accum(const float* __restrict__ x,
                                                  float* __restrict__ part) {
    // per-wave row: [2 guard][64 bins][2 guard][pad] = 128 floats; 4 waves = 2 KB
    __shared__ float wh[4][128];
    const int ch  = blockIdx.x >> 6;
    const int sub = blockIdx.x & 63;
    const int tid = threadIdx.x;
    const int wid = tid >> 6;

    // zero-init 512 words with 256 threads
    float* whf = &wh[0][0];
    whf[tid] = 0.0f;
    whf[256 + tid] = 0.0f;
    __syncthreads();

    // 1024 px per block = 256 float4; one float4 per thread, coalesced
    const float4 v = reinterpret_cast<const float4*>(x)[ch * (HW / 4) + sub * 256 + tid];

    // LDS byte address of this wave's row (+2-bin guard offset folded in below)
    const uint32_t base = (uint32_t)(uintptr_t)(&wh[wid][0]);

    float px[4] = {v.x, v.y, v.z, v.w};
#pragma unroll
    for (int q = 0; q < 4; ++q) {
        const float pp = 63.0f * px[q];
        const float kf = rintf(pp);
        const float d0 = (pp - kf) * DELTA;   // p - nearest bin val
        const int   ki = (int)kf;             // 0..63
        float w[5];
#pragma unroll
        for (int m = 0; m < 5; ++m) {
            const float d = d0 - (float)(m - 2) * DELTA;
            w[m] = __builtin_amdgcn_exp2f(d * (d * EXP_C));
        }
        // row slots: bin j at LDS index j+2; bins ki-2..ki+2 -> indices ki..ki+4
        const uint32_t addr = base + (uint32_t)(ki << 2);
        asm volatile("ds_add_f32 %0, %1"            :: "v"(addr), "v"(w[0]) : "memory");
        asm volatile("ds_add_f32 %0, %1 offset:4"   :: "v"(addr), "v"(w[1]) : "memory");
        asm volatile("ds_add_f32 %0, %1 offset:8"   :: "v"(addr), "v"(w[2]) : "memory");
        asm volatile("ds_add_f32 %0, %1 offset:12"  :: "v"(addr), "v"(w[3]) : "memory");
        asm volatile("ds_add_f32 %0, %1 offset:16"  :: "v"(addr), "v"(w[4]) : "memory");
    }
    __syncthreads();   // drains lgkmcnt -> all ds_add complete

    // combine 4 wave rows; 64 threads, coalesced store of this block's partial
    if (tid < NBIN) {
        const float s = (wh[0][2 + tid] + wh[1][2 + tid]) +
                        (wh[2][2 + tid] + wh[3][2 + tid]);
        part[(ch * BPC + sub) * NBIN + tid] = s;
    }
}

__global__ __launch_bounds__(256) void hist_norm(const float* __restrict__ part,
                                                 float* __restrict__ out) {
    const int ch  = blockIdx.x;
    const int t   = threadIdx.x;
    const int bin = t & 63;
    const int grp = t >> 6;            // 0..3
    const float* p = part + ch * (BPC * NBIN);
    float s = 0.0f;
#pragma unroll
    for (int i = 0; i < 16; ++i)       // each grp reduces 16 of the 64 sub-partials
        s += p[(grp * 16 + i) * NBIN + bin];
    __shared__ float sacc[4][NBIN];
    sacc[grp][bin] = s;
    __syncthreads();
    if (grp == 0) {                    // one wave finishes: total + normalize
        const float h = (sacc[0][bin] + sacc[1][bin]) + (sacc[2][bin] + sacc[3][bin]);
        float tot = h;
        tot += __shfl_xor(tot, 32);
        tot += __shfl_xor(tot, 16);
        tot += __shfl_xor(tot, 8);
        tot += __shfl_xor(tot, 4);
        tot += __shfl_xor(tot, 2);
        tot += __shfl_xor(tot, 1);
        out[ch * NBIN + bin] = h / (tot + 1e-8f);
    }
}

extern "C" void kernel_launch(void* const* d_in, const int* in_sizes, int n_in,
                              void* d_out, int out_size, void* d_ws, size_t ws_size,
                              hipStream_t stream) {
    const float* x = (const float*)d_in[0];
    float* part = (float*)d_ws;        // 24*64*64*4 = 384 KB, fully overwritten

    hist_accum<<<NCH * BPC, 256, 0, stream>>>(x, part);
    hist_norm<<<NCH, 256, 0, stream>>>(part, (float*)d_out);
}

// Round 11
// 62.636 us; speedup vs baseline: 1.8207x; 1.5447x over previous
//
#include <hip/hip_runtime.h>
#include <hip/hip_fp16.h>

// RGBuvHistBlock: soft histogram, 64 bins in [-1,1], sigma=0.02.
// Accum ladder: CAS atomicAdd 71.7us (R3) | ds_add_f32 42.2us (R10) |
// private-column f32 RMW 8.8us (R8) -> this: f16-PACKED private columns.
// Window aligned to even base kb=ki&~1: 6 weights for bins kb-2..kb+3
// (superset of ki+/-2; WIN truncation absmax 1.22e-4 vs 3.42e-4 threshold).
// 3x {ds_read_b32, v_pk_add_f16, ds_write_b32} per px (vs 10 DS ops in R8),
// column = tid -> bank = tid%32, 2 lanes/bank = free. 256 thr/block, 36KB LDS
// -> 12 waves/CU (2x R8's occupancy) to hide the read->add->write latency.
// f16 error: column max ~8, rounding random-walk ~1e-6 normalized; weights
// <6e-5 flush to 0, already inside the window-truncation budget.
// Fixed overhead in timed window (measured R10): ws-poison fill 40.5us +
// ~14us restore/fills/norm/gaps = 54.5us not kernel-addressable.

#define NCH   24        // 8*3 channels
#define HW    65536     // 256*256
#define BPC   32        // blocks per channel (2048 px each)
#define NBIN  64
#define NROWS 36        // 1 guard pair-row + 32 pair-rows + 1 guard + 2 pad
#define NCOL  256       // one column per thread
// K2 = -(2/63)^2 * 1250 * log2(e)  (weight = exp2(K2 * (pp - j)^2), pp = 63x)
#define K2 ((float)(-(2.0/63.0)*(2.0/63.0)*1250.0*1.4426950408889634))

__global__ __launch_bounds__(256) void hist_accum(const float* __restrict__ x,
                                                  float* __restrict__ part) {
    __shared__ __half2 hist[NROWS][NCOL];        // 36 KB -> 3 blocks/CU (grid-limited)
    const int ch  = blockIdx.x >> 5;
    const int sub = blockIdx.x & 31;
    const int tid = threadIdx.x;

    // zero-init: 36*256 half2 = 9216 words = 2304 float4; 256 threads x 9
    float4* hz = reinterpret_cast<float4*>(&hist[0][0]);
#pragma unroll
    for (int i = 0; i < 9; ++i) hz[i * 256 + tid] = float4{0.f, 0.f, 0.f, 0.f};
    __syncthreads();

    // 2048 px per block = 512 float4; 256 threads x 2, coalesced
    const float4* xv = reinterpret_cast<const float4*>(x) + ch * (HW / 4) + sub * 512;
    const float4 v0 = xv[tid];
    const float4 v1 = xv[256 + tid];
    float px[8] = {v0.x, v0.y, v0.z, v0.w, v1.x, v1.y, v1.z, v1.w};

#pragma unroll
    for (int q = 0; q < 8; ++q) {
        const float pp = 63.0f * px[q];          // bin-units position in [0,63)
        const int   ki = (int)rintf(pp);         // nearest bin 0..63
        const int   kb = ki & ~1;                // even-aligned window base
        const float f  = pp - (float)kb;         // in [-0.5, 1.5]
        float w[6];
#pragma unroll
        for (int m = 0; m < 6; ++m) {            // bins kb-2 .. kb+3
            const float t = f - (float)(m - 2);
            w[m] = __builtin_amdgcn_exp2f(t * t * K2);
        }
        const __half2 h0 = __floats2half2_rn(w[0], w[1]);
        const __half2 h1 = __floats2half2_rn(w[2], w[3]);
        const __half2 h2 = __floats2half2_rn(w[4], w[5]);
        // pair-row for bins (kb-2,kb-1) is (kb>>1)-1; +1 guard shift -> kb>>1
        __half2* col = &hist[kb >> 1][tid];      // rows at +0, +NCOL, +2*NCOL
        col[0]        = __hadd2(col[0],        h0);
        col[NCOL]     = __hadd2(col[NCOL],     h1);
        col[2 * NCOL] = __hadd2(col[2 * NCOL], h2);
    }
    __syncthreads();

    // reduce: wave w -> pair-rows 1+8w .. 8+8w (bins 16w .. 16w+15).
    // lane reads 4 consecutive half2 (16B, b128), unpacks to f32, shuffle-reduces.
    const int wid  = tid >> 6;
    const int lane = tid & 63;
    float* pout = part + (ch * BPC + sub) * NBIN;
#pragma unroll
    for (int r = 0; r < 8; ++r) {
        const int s = 1 + wid * 8 + r;
        const __half2* hp = &hist[s][lane * 4];
        const float2 t0 = __half22float2(hp[0]);
        const float2 t1 = __half22float2(hp[1]);
        const float2 t2 = __half22float2(hp[2]);
        const float2 t3 = __half22float2(hp[3]);
        float fe = (t0.x + t1.x) + (t2.x + t3.x);   // even bin 2(s-1)
        float fo = (t0.y + t1.y) + (t2.y + t3.y);   // odd  bin 2(s-1)+1
#pragma unroll
        for (int d = 1; d < 64; d <<= 1) {
            fe += __shfl_xor(fe, d);
            fo += __shfl_xor(fo, d);
        }
        if (lane == 0)
            *reinterpret_cast<float2*>(&pout[2 * (s - 1)]) = float2{fe, fo};
    }
}

__global__ __launch_bounds__(256) void hist_norm(const float* __restrict__ part,
                                                 float* __restrict__ out) {
    const int ch  = blockIdx.x;
    const int t   = threadIdx.x;
    const int bin = t & 63;
    const int grp = t >> 6;            // 0..3
    const float* p = part + ch * (BPC * NBIN);
    float s = 0.0f;
#pragma unroll
    for (int i = 0; i < 8; ++i)        // each grp reduces 8 of the 32 sub-partials
        s += p[(grp * 8 + i) * NBIN + bin];
    __shared__ float sacc[4][NBIN];
    sacc[grp][bin] = s;
    __syncthreads();
    if (grp == 0) {                    // one wave finishes: total + normalize
        const float h = (sacc[0][bin] + sacc[1][bin]) + (sacc[2][bin] + sacc[3][bin]);
        float tot = h;
        tot += __shfl_xor(tot, 32);
        tot += __shfl_xor(tot, 16);
        tot += __shfl_xor(tot, 8);
        tot += __shfl_xor(tot, 4);
        tot += __shfl_xor(tot, 2);
        tot += __shfl_xor(tot, 1);
        out[ch * NBIN + bin] = h / (tot + 1e-8f);
    }
}

extern "C" void kernel_launch(void* const* d_in, const int* in_sizes, int n_in,
                              void* d_out, int out_size, void* d_ws, size_t ws_size,
                              hipStream_t stream) {
    const float* x = (const float*)d_in[0];
    float* part = (float*)d_ws;        // 24*32*64*4 = 192 KB, fully overwritten

    hist_accum<<<NCH * BPC, 256, 0, stream>>>(x, part);
    hist_norm<<<NCH, 256, 0, stream>>>(part, (float*)d_out);
}